// Round 1
// baseline (897.051 us; speedup 1.0000x reference)
//
#include <hip/hip_runtime.h>
#include <hip/hip_bf16.h>
#include <math.h>

// Problem constants (validated against in_sizes at launch where cheap).
#define D_IN   256
#define D_OUT  128
#define DZ     384   // [low | high | mlp] concatenated

// ---------------------------------------------------------------------------
// K0: Z[m, 0:384] = x[m, :] @ [W_low | W_high | W_mlp]
// fp32 tiled GEMM, BM=64 BN=64 BK=16, 256 threads, 4x4 micro-tile per thread.
// ---------------------------------------------------------------------------
#define BM 64
#define BN 64
#define BK 16

__global__ __launch_bounds__(256) void gemm_kernel(
    const float* __restrict__ x,
    const float* __restrict__ Wl, const float* __restrict__ Wh,
    const float* __restrict__ Wm,
    float* __restrict__ Z, int n_nodes) {
  __shared__ float As[BK][BM + 4];  // [k][m], padded for alignment/banks
  __shared__ float Bs[BK][BN + 4];  // [k][n]

  const int tid = threadIdx.x;
  const int bm = blockIdx.x * BM;
  const int bn = blockIdx.y * BN;  // 0..5 * 64 -> boundaries align with the 3 Ws

  const float* W = (blockIdx.y < 2) ? Wl : (blockIdx.y < 4 ? Wh : Wm);
  const int ncol0 = bn & 127;  // column offset within the selected 128-wide W

  const int tn = (tid & 15) * 4;  // 16 threads across N
  const int tm = (tid >> 4) * 4;  // 16 threads across M

  float acc[4][4] = {};

  const int ka = tid & 15;   // k for A loads
  const int ma = tid >> 4;   // base m for A loads (0..15)
  const int nb = tid & 63;   // n for B loads
  const int kb = tid >> 6;   // base k for B loads (0..3)

  for (int k0 = 0; k0 < D_IN; k0 += BK) {
#pragma unroll
    for (int i = 0; i < 4; i++) {
      int m = ma + i * 16;
      int gm = bm + m;
      float v = 0.f;
      if (gm < n_nodes) v = x[(size_t)gm * D_IN + k0 + ka];
      As[ka][m] = v;
    }
#pragma unroll
    for (int i = 0; i < 4; i++) {
      int k = kb + i * 4;
      Bs[k][nb] = W[(size_t)(k0 + k) * D_OUT + ncol0 + nb];
    }
    __syncthreads();
#pragma unroll
    for (int k = 0; k < BK; k++) {
      float a[4], b[4];
#pragma unroll
      for (int i = 0; i < 4; i++) a[i] = As[k][tm + i];
#pragma unroll
      for (int j = 0; j < 4; j++) b[j] = Bs[k][tn + j];
#pragma unroll
      for (int i = 0; i < 4; i++)
#pragma unroll
        for (int j = 0; j < 4; j++) acc[i][j] += a[i] * b[j];
    }
    __syncthreads();
  }

#pragma unroll
  for (int i = 0; i < 4; i++) {
    int gm = bm + tm + i;
    if (gm < n_nodes) {
      float4 v = make_float4(acc[i][0], acc[i][1], acc[i][2], acc[i][3]);
      *(float4*)&Z[(size_t)gm * DZ + bn + tn] = v;
    }
  }
}

// ---------------------------------------------------------------------------
// K1/K2: per-dst linked list over edges (no scan needed).
// ---------------------------------------------------------------------------
__global__ void init_head_kernel(int* __restrict__ head, int n) {
  int i = blockIdx.x * blockDim.x + threadIdx.x;
  if (i < n) head[i] = -1;
}

__global__ void build_links_kernel(const int* __restrict__ dst,
                                   int* __restrict__ head,
                                   int* __restrict__ nxt, int n_edges) {
  int e = blockIdx.x * blockDim.x + threadIdx.x;
  if (e < n_edges) nxt[e] = atomicExch(&head[dst[e]], e);
}

// ---------------------------------------------------------------------------
// K3: per-node fused SPMM-gather + relu + attention3 epilogue.
// One block of 128 threads per node; thread d owns output dim d.
// ---------------------------------------------------------------------------
__global__ __launch_bounds__(128) void node_kernel(
    const float* __restrict__ Z, const int* __restrict__ head,
    const int* __restrict__ nxt, const int* __restrict__ src,
    const float* __restrict__ wlo, const float* __restrict__ whi,
    const float* __restrict__ a_low, const float* __restrict__ a_high,
    const float* __restrict__ a_mlp, const float* __restrict__ att_vec,
    float* __restrict__ out) {
  const int node = blockIdx.x;
  const int d = threadIdx.x;  // 0..127

  float acc_lo = 0.f, acc_hi = 0.f;
  int e = head[node];
  while (e != -1) {
    int s = src[e];
    float wl = wlo[e];
    float wh = whi[e];
    int en = nxt[e];
    const float* zr = Z + (size_t)s * DZ;
    acc_lo += wl * zr[d];
    acc_hi += wh * zr[D_OUT + d];
    e = en;
  }

  float h_lo = fmaxf(acc_lo, 0.f);
  float h_hi = fmaxf(acc_hi, 0.f);
  float h_ml = fmaxf(Z[(size_t)node * DZ + 2 * D_OUT + d], 0.f);

  // three 128-dim dots -> block reduce (2 waves of 64)
  float p0 = h_lo * a_low[d];
  float p1 = h_hi * a_high[d];
  float p2 = h_ml * a_mlp[d];
#pragma unroll
  for (int off = 1; off < 64; off <<= 1) {
    p0 += __shfl_xor(p0, off);
    p1 += __shfl_xor(p1, off);
    p2 += __shfl_xor(p2, off);
  }
  __shared__ float red[2][3];
  int wave = d >> 6;
  if ((d & 63) == 0) {
    red[wave][0] = p0;
    red[wave][1] = p1;
    red[wave][2] = p2;
  }
  __syncthreads();
  float s0 = red[0][0] + red[1][0];
  float s1 = red[0][1] + red[1][1];
  float s2 = red[0][2] + red[1][2];

  // sigmoid -> 3x3 mix / 3 -> softmax (T=3) -> combine * 3
  float g0 = 1.f / (1.f + __expf(-s0));
  float g1 = 1.f / (1.f + __expf(-s1));
  float g2 = 1.f / (1.f + __expf(-s2));
  const float inv3 = 1.f / 3.f;
  float m0 = (g0 * att_vec[0] + g1 * att_vec[3] + g2 * att_vec[6]) * inv3;
  float m1 = (g0 * att_vec[1] + g1 * att_vec[4] + g2 * att_vec[7]) * inv3;
  float m2 = (g0 * att_vec[2] + g1 * att_vec[5] + g2 * att_vec[8]) * inv3;
  float mx = fmaxf(m0, fmaxf(m1, m2));
  float e0 = __expf(m0 - mx), e1 = __expf(m1 - mx), e2 = __expf(m2 - mx);
  float inv = 1.f / (e0 + e1 + e2);
  float o = 3.f * inv * (e0 * h_lo + e1 * h_hi + e2 * h_ml);
  out[(size_t)node * D_OUT + d] = o;
}

// ---------------------------------------------------------------------------
extern "C" void kernel_launch(void* const* d_in, const int* in_sizes, int n_in,
                              void* d_out, int out_size, void* d_ws,
                              size_t ws_size, hipStream_t stream) {
  const float* x    = (const float*)d_in[0];
  const int*   esrc = (const int*)d_in[1];
  const int*   edst = (const int*)d_in[2];
  const float* wlo  = (const float*)d_in[3];
  const float* whi  = (const float*)d_in[4];
  // d_in[5] = w_unnorm: unused by the reference
  const float* Wl   = (const float*)d_in[6];
  const float* Wh   = (const float*)d_in[7];
  const float* Wm   = (const float*)d_in[8];
  const float* alo  = (const float*)d_in[9];
  const float* ahi  = (const float*)d_in[10];
  const float* amlp = (const float*)d_in[11];
  const float* av   = (const float*)d_in[12];
  float* out = (float*)d_out;

  const int N = in_sizes[0] / D_IN;  // 100000
  const int E = in_sizes[1];         // 1600000

  // Workspace layout: Z [N*384 f32] | head [N int] | nxt [E int]
  char* ws = (char*)d_ws;
  size_t zbytes = ((size_t)N * DZ * sizeof(float) + 255) & ~(size_t)255;
  float* Z = (float*)ws;
  int* head = (int*)(ws + zbytes);
  size_t hbytes = ((size_t)N * sizeof(int) + 255) & ~(size_t)255;
  int* nxt = (int*)(ws + zbytes + hbytes);

  dim3 ggrid((N + BM - 1) / BM, DZ / BN);
  gemm_kernel<<<ggrid, 256, 0, stream>>>(x, Wl, Wh, Wm, Z, N);

  init_head_kernel<<<(N + 255) / 256, 256, 0, stream>>>(head, N);
  build_links_kernel<<<(E + 255) / 256, 256, 0, stream>>>(edst, head, nxt, E);

  node_kernel<<<N, 128, 0, stream>>>(Z, head, nxt, esrc, wlo, whi, alo, ahi,
                                     amlp, av, out);
}

// Round 2
// 698.140 us; speedup vs baseline: 1.2849x; 1.2849x over previous
//
#include <hip/hip_runtime.h>
#include <hip/hip_bf16.h>
#include <math.h>

#define D_IN   256
#define D_OUT  128
#define DZ     384   // [low | high | mlp]

typedef __attribute__((ext_vector_type(8))) short short8;
typedef __attribute__((ext_vector_type(4))) float floatx4;

__device__ __forceinline__ unsigned short f2bf(float f) {
  union { float f; unsigned u; } v; v.f = f;
  unsigned r = v.u + 0x7fffu + ((v.u >> 16) & 1u);  // RNE
  return (unsigned short)(r >> 16);
}

// ---------------------------------------------------------------------------
// K0: pack [Wl|Wh|Wm] (fp32, 256x384 logical) into MFMA B-fragment order:
// frag f = kt*24+nt holds B[k=kt*32+quad*8+j][n=nt*16+(lane&15)]
// flat index t = f*512 + lane*8 + j  -> contiguous 16B/lane loads in GEMM.
// ---------------------------------------------------------------------------
__global__ void repack_w_kernel(const float* __restrict__ Wl,
                                const float* __restrict__ Wh,
                                const float* __restrict__ Wm,
                                unsigned short* __restrict__ Bpack) {
  int t = blockIdx.x * 256 + threadIdx.x;  // 0..98303
  int j = t & 7;
  int lane = (t >> 3) & 63;
  int f = t >> 9;          // 0..191
  int nt = f % 24, kt = f / 24;
  int k = kt * 32 + (lane >> 4) * 8 + j;
  int n = nt * 16 + (lane & 15);
  const float* W = (n < 128) ? Wl : (n < 256 ? Wh : Wm);
  Bpack[t] = f2bf(W[k * D_OUT + (n & 127)]);
}

// ---------------------------------------------------------------------------
// K1: Z[100000, 384] (bf16) = x @ [Wl|Wh|Wm] via 16x16x32 bf16 MFMA.
// One wave per 16-row strip, 24 column tiles, K-loop of 8. No LDS.
// ---------------------------------------------------------------------------
__global__ __launch_bounds__(256) void gemm_kernel(
    const float* __restrict__ x, const unsigned short* __restrict__ Bpack,
    unsigned short* __restrict__ Z, int n_strips) {
  const int lane = threadIdx.x & 63;
  const int strip = blockIdx.x * 4 + (threadIdx.x >> 6);
  if (strip >= n_strips) return;
  const int m16 = lane & 15, quad = lane >> 4;

  floatx4 acc[24];
#pragma unroll
  for (int i = 0; i < 24; i++) acc[i] = (floatx4)(0.f);

  const float* xr = x + (size_t)(strip * 16 + m16) * D_IN + quad * 8;
  const short8* bp = (const short8*)Bpack + lane;  // + f*64 per fragment

#pragma unroll
  for (int kt = 0; kt < 8; kt++) {
    float4 f0 = ((const float4*)(xr + kt * 32))[0];
    float4 f1 = ((const float4*)(xr + kt * 32))[1];
    short8 a;
    a[0] = (short)f2bf(f0.x); a[1] = (short)f2bf(f0.y);
    a[2] = (short)f2bf(f0.z); a[3] = (short)f2bf(f0.w);
    a[4] = (short)f2bf(f1.x); a[5] = (short)f2bf(f1.y);
    a[6] = (short)f2bf(f1.z); a[7] = (short)f2bf(f1.w);
#pragma unroll
    for (int nt = 0; nt < 24; nt++) {
      short8 b = bp[(kt * 24 + nt) * 64];
      acc[nt] = __builtin_amdgcn_mfma_f32_16x16x32_bf16(a, b, acc[nt], 0, 0, 0);
    }
  }

#pragma unroll
  for (int nt = 0; nt < 24; nt++) {
#pragma unroll
    for (int r = 0; r < 4; r++) {
      int row = strip * 16 + quad * 4 + r;  // C/D: col=lane&15, row=quad*4+reg
      Z[(size_t)row * DZ + nt * 16 + m16] = f2bf(acc[nt][r]);
    }
  }
}

// ---------------------------------------------------------------------------
// CSR build: count -> scan (3 kernels) -> fill (materialize sorted edge data)
// ---------------------------------------------------------------------------
__global__ void count_kernel(const int* __restrict__ dst, int* __restrict__ cnt,
                             int E) {
  int e = blockIdx.x * 256 + threadIdx.x;
  if (e < E) atomicAdd(&cnt[dst[e]], 1);
}

__global__ __launch_bounds__(256) void scan1_kernel(
    const int* __restrict__ cnt, int* __restrict__ rowptr,
    int* __restrict__ bsum, int n) {
  __shared__ int sd[256];
  int t = threadIdx.x;
  int base = blockIdx.x * 1024 + t * 4;
  int v0 = base + 0 < n ? cnt[base + 0] : 0;
  int v1 = base + 1 < n ? cnt[base + 1] : 0;
  int v2 = base + 2 < n ? cnt[base + 2] : 0;
  int v3 = base + 3 < n ? cnt[base + 3] : 0;
  int tsum = v0 + v1 + v2 + v3;
  sd[t] = tsum;
  __syncthreads();
  for (int off = 1; off < 256; off <<= 1) {
    int add = (t >= off) ? sd[t - off] : 0;
    __syncthreads();
    sd[t] += add;
    __syncthreads();
  }
  int excl = sd[t] - tsum;
  if (base + 0 < n) rowptr[base + 0] = excl;
  if (base + 1 < n) rowptr[base + 1] = excl + v0;
  if (base + 2 < n) rowptr[base + 2] = excl + v0 + v1;
  if (base + 3 < n) rowptr[base + 3] = excl + v0 + v1 + v2;
  if (t == 255) bsum[blockIdx.x] = sd[255];
}

__global__ __launch_bounds__(128) void scan2_kernel(int* __restrict__ bsum,
                                                    int nb) {
  __shared__ int sd[128];
  int t = threadIdx.x;
  int v = t < nb ? bsum[t] : 0;
  sd[t] = v;
  __syncthreads();
  for (int off = 1; off < 128; off <<= 1) {
    int add = (t >= off) ? sd[t - off] : 0;
    __syncthreads();
    sd[t] += add;
    __syncthreads();
  }
  if (t < nb) bsum[t] = sd[t] - v;  // exclusive
}

__global__ void scan3_kernel(int* __restrict__ rowptr, int* __restrict__ cursor,
                             const int* __restrict__ bsum, int n) {
  int i = blockIdx.x * 256 + threadIdx.x;
  if (i < n) {
    int r = rowptr[i] + bsum[i >> 10];
    rowptr[i] = r;
    cursor[i] = r;
  }
}

__global__ void fill_kernel(const int* __restrict__ src,
                            const int* __restrict__ dst,
                            const float* __restrict__ wlo,
                            const float* __restrict__ whi,
                            int* __restrict__ cursor, int* __restrict__ srcS,
                            float* __restrict__ wlS, float* __restrict__ whS,
                            int E) {
  int e = blockIdx.x * 256 + threadIdx.x;
  if (e < E) {
    int d = dst[e];
    int pos = atomicAdd(&cursor[d], 1);
    srcS[pos] = src[e];
    wlS[pos] = wlo[e];
    whS[pos] = whi[e];
  }
}

// ---------------------------------------------------------------------------
// K_node: CSR gather (bf16 Z) + relu + attention3. One wave per node;
// lane d owns dims 2d, 2d+1 (uint = bf16 pair -> 4B coalesced loads).
// ---------------------------------------------------------------------------
__global__ __launch_bounds__(64) void node_kernel(
    const unsigned int* __restrict__ ZU, const int* __restrict__ rowptr,
    const int* __restrict__ cnt, const int* __restrict__ srcS,
    const float* __restrict__ wlS, const float* __restrict__ whS,
    const float* __restrict__ a_low, const float* __restrict__ a_high,
    const float* __restrict__ a_mlp, const float* __restrict__ att_vec,
    float* __restrict__ out) {
  const int node = blockIdx.x;
  const int d = threadIdx.x;  // 0..63
  const int start = rowptr[node];
  const int end = start + cnt[node];

  float lo0 = 0.f, lo1 = 0.f, hi0 = 0.f, hi1 = 0.f;
  int j = start;
  for (; j + 1 < end; j += 2) {
    int s0 = srcS[j], s1 = srcS[j + 1];
    float wl0 = wlS[j], wl1 = wlS[j + 1];
    float wh0 = whS[j], wh1 = whS[j + 1];
    const unsigned* z0 = ZU + (size_t)s0 * 192;
    const unsigned* z1 = ZU + (size_t)s1 * 192;
    unsigned ul0 = z0[d], uh0 = z0[64 + d];
    unsigned ul1 = z1[d], uh1 = z1[64 + d];
    lo0 += wl0 * __uint_as_float(ul0 << 16);
    lo1 += wl0 * __uint_as_float(ul0 & 0xffff0000u);
    hi0 += wh0 * __uint_as_float(uh0 << 16);
    hi1 += wh0 * __uint_as_float(uh0 & 0xffff0000u);
    lo0 += wl1 * __uint_as_float(ul1 << 16);
    lo1 += wl1 * __uint_as_float(ul1 & 0xffff0000u);
    hi0 += wh1 * __uint_as_float(uh1 << 16);
    hi1 += wh1 * __uint_as_float(uh1 & 0xffff0000u);
  }
  if (j < end) {
    int s0 = srcS[j];
    float wl0 = wlS[j], wh0 = whS[j];
    const unsigned* z0 = ZU + (size_t)s0 * 192;
    unsigned ul0 = z0[d], uh0 = z0[64 + d];
    lo0 += wl0 * __uint_as_float(ul0 << 16);
    lo1 += wl0 * __uint_as_float(ul0 & 0xffff0000u);
    hi0 += wh0 * __uint_as_float(uh0 << 16);
    hi1 += wh0 * __uint_as_float(uh0 & 0xffff0000u);
  }

  float hlo0 = fmaxf(lo0, 0.f), hlo1 = fmaxf(lo1, 0.f);
  float hhi0 = fmaxf(hi0, 0.f), hhi1 = fmaxf(hi1, 0.f);
  unsigned um = ZU[(size_t)node * 192 + 128 + d];
  float hml0 = fmaxf(__uint_as_float(um << 16), 0.f);
  float hml1 = fmaxf(__uint_as_float(um & 0xffff0000u), 0.f);

  float p0 = hlo0 * a_low[2 * d] + hlo1 * a_low[2 * d + 1];
  float p1 = hhi0 * a_high[2 * d] + hhi1 * a_high[2 * d + 1];
  float p2 = hml0 * a_mlp[2 * d] + hml1 * a_mlp[2 * d + 1];
#pragma unroll
  for (int off = 1; off < 64; off <<= 1) {
    p0 += __shfl_xor(p0, off);
    p1 += __shfl_xor(p1, off);
    p2 += __shfl_xor(p2, off);
  }

  float g0 = 1.f / (1.f + __expf(-p0));
  float g1 = 1.f / (1.f + __expf(-p1));
  float g2 = 1.f / (1.f + __expf(-p2));
  const float inv3 = 1.f / 3.f;
  float m0 = (g0 * att_vec[0] + g1 * att_vec[3] + g2 * att_vec[6]) * inv3;
  float m1 = (g0 * att_vec[1] + g1 * att_vec[4] + g2 * att_vec[7]) * inv3;
  float m2 = (g0 * att_vec[2] + g1 * att_vec[5] + g2 * att_vec[8]) * inv3;
  float mx = fmaxf(m0, fmaxf(m1, m2));
  float e0 = __expf(m0 - mx), e1 = __expf(m1 - mx), e2 = __expf(m2 - mx);
  float inv = 1.f / (e0 + e1 + e2);
  float2 o;
  o.x = 3.f * inv * (e0 * hlo0 + e1 * hhi0 + e2 * hml0);
  o.y = 3.f * inv * (e0 * hlo1 + e1 * hhi1 + e2 * hml1);
  *(float2*)&out[(size_t)node * D_OUT + 2 * d] = o;
}

// ---------------------------------------------------------------------------
extern "C" void kernel_launch(void* const* d_in, const int* in_sizes, int n_in,
                              void* d_out, int out_size, void* d_ws,
                              size_t ws_size, hipStream_t stream) {
  const float* x    = (const float*)d_in[0];
  const int*   esrc = (const int*)d_in[1];
  const int*   edst = (const int*)d_in[2];
  const float* wlo  = (const float*)d_in[3];
  const float* whi  = (const float*)d_in[4];
  const float* Wl   = (const float*)d_in[6];
  const float* Wh   = (const float*)d_in[7];
  const float* Wm   = (const float*)d_in[8];
  const float* alo  = (const float*)d_in[9];
  const float* ahi  = (const float*)d_in[10];
  const float* amlp = (const float*)d_in[11];
  const float* av   = (const float*)d_in[12];
  float* out = (float*)d_out;

  const int N = in_sizes[0] / D_IN;  // 100000 (divisible by 16)
  const int E = in_sizes[1];         // 1600000

  char* ws = (char*)d_ws;
  size_t off = 0;
  auto carve = [&](size_t bytes) -> void* {
    void* p = ws + off;
    off = (off + bytes + 255) & ~(size_t)255;
    return p;
  };
  unsigned short* Z      = (unsigned short*)carve((size_t)N * DZ * 2);
  unsigned short* Bpack  = (unsigned short*)carve(98304 * 2);
  int*   cnt    = (int*)carve((size_t)N * 4);
  int*   rowptr = (int*)carve((size_t)N * 4);
  int*   cursor = (int*)carve((size_t)N * 4);
  int*   bsum   = (int*)carve(128 * 4);
  int*   srcS   = (int*)carve((size_t)E * 4);
  float* wlS    = (float*)carve((size_t)E * 4);
  float* whS    = (float*)carve((size_t)E * 4);

  repack_w_kernel<<<384, 256, 0, stream>>>(Wl, Wh, Wm, Bpack);

  const int n_strips = N / 16;
  gemm_kernel<<<(n_strips + 3) / 4, 256, 0, stream>>>(x, Bpack, Z, n_strips);

  hipMemsetAsync(cnt, 0, (size_t)N * 4, stream);
  count_kernel<<<(E + 255) / 256, 256, 0, stream>>>(edst, cnt, E);
  int nb = (N + 1023) / 1024;  // 98 <= 128
  scan1_kernel<<<nb, 256, 0, stream>>>(cnt, rowptr, bsum, N);
  scan2_kernel<<<1, 128, 0, stream>>>(bsum, nb);
  scan3_kernel<<<(N + 255) / 256, 256, 0, stream>>>(rowptr, cursor, bsum, N);
  fill_kernel<<<(E + 255) / 256, 256, 0, stream>>>(esrc, edst, wlo, whi, cursor,
                                                   srcS, wlS, whS, E);

  node_kernel<<<N, 64, 0, stream>>>((const unsigned int*)Z, rowptr, cnt, srcS,
                                    wlS, whS, alo, ahi, amlp, av, out);
}

// Round 3
// 564.091 us; speedup vs baseline: 1.5903x; 1.2376x over previous
//
#include <hip/hip_runtime.h>
#include <hip/hip_bf16.h>
#include <math.h>

#define D_IN   256
#define D_OUT  128
#define DZ     384   // [low | high | mlp] bf16, 768 B per row

typedef __attribute__((ext_vector_type(8))) short short8;
typedef __attribute__((ext_vector_type(4))) float floatx4;

__device__ __forceinline__ unsigned short f2bf(float f) {
  union { float f; unsigned u; } v; v.f = f;
  unsigned r = v.u + 0x7fffu + ((v.u >> 16) & 1u);  // RNE
  return (unsigned short)(r >> 16);
}

// ---------------------------------------------------------------------------
// K0: pack [Wl|Wh|Wm] into MFMA B-fragment order.
// frag f = kt*24+nt holds B[k=kt*32+quad*8+j][n=nt*16+(lane&15)]
// flat index t = f*512 + lane*8 + j.
// ---------------------------------------------------------------------------
__global__ void repack_w_kernel(const float* __restrict__ Wl,
                                const float* __restrict__ Wh,
                                const float* __restrict__ Wm,
                                unsigned short* __restrict__ Bpack) {
  int t = blockIdx.x * 256 + threadIdx.x;  // 0..98303
  int j = t & 7;
  int lane = (t >> 3) & 63;
  int f = t >> 9;          // 0..191
  int nt = f % 24, kt = f / 24;
  int k = kt * 32 + (lane >> 4) * 8 + j;
  int n = nt * 16 + (lane & 15);
  const float* W = (n < 128) ? Wl : (n < 256 ? Wh : Wm);
  Bpack[t] = f2bf(W[k * D_OUT + (n & 127)]);
}

// ---------------------------------------------------------------------------
// K1: Z = x @ [Wl|Wh|Wm], bf16 MFMA, 64x96 wave tile.
// Block = 256 threads = 4 waves over the same 64 rows; wave w owns col tiles
// w*6..w*6+5. acc 4x6 (96 AGPR): B frag reused 4x, A frag 6x. No LDS,
// no barriers -> loads pipeline freely across the unrolled kt loop.
// ---------------------------------------------------------------------------
__global__ __launch_bounds__(256) void gemm_kernel(
    const float* __restrict__ x, const unsigned short* __restrict__ Bpack,
    unsigned short* __restrict__ Z, int n_nodes) {
  const int lane = threadIdx.x & 63;
  const int w = threadIdx.x >> 6;        // wave id: column group
  const int rowbase = blockIdx.x * 64;
  const int m16 = lane & 15, quad = lane >> 4;

  floatx4 acc[4][6];
#pragma unroll
  for (int s = 0; s < 4; s++)
#pragma unroll
    for (int c = 0; c < 6; c++) acc[s][c] = (floatx4)(0.f);

  const float* xr[4];
#pragma unroll
  for (int s = 0; s < 4; s++) {
    int r = rowbase + s * 16 + m16;
    if (r > n_nodes - 1) r = n_nodes - 1;  // clamp; stores are guarded
    xr[s] = x + (size_t)r * D_IN + quad * 8;
  }
  const short8* bp = (const short8*)Bpack + lane;

#pragma unroll
  for (int kt = 0; kt < 8; kt++) {
    short8 a[4];
#pragma unroll
    for (int s = 0; s < 4; s++) {
      float4 f0 = ((const float4*)(xr[s] + kt * 32))[0];
      float4 f1 = ((const float4*)(xr[s] + kt * 32))[1];
      a[s][0] = (short)f2bf(f0.x); a[s][1] = (short)f2bf(f0.y);
      a[s][2] = (short)f2bf(f0.z); a[s][3] = (short)f2bf(f0.w);
      a[s][4] = (short)f2bf(f1.x); a[s][5] = (short)f2bf(f1.y);
      a[s][6] = (short)f2bf(f1.z); a[s][7] = (short)f2bf(f1.w);
    }
#pragma unroll
    for (int c = 0; c < 6; c++) {
      short8 b = bp[(kt * 24 + w * 6 + c) * 64];
#pragma unroll
      for (int s = 0; s < 4; s++)
        acc[s][c] =
            __builtin_amdgcn_mfma_f32_16x16x32_bf16(a[s], b, acc[s][c], 0, 0, 0);
    }
  }

#pragma unroll
  for (int s = 0; s < 4; s++)
#pragma unroll
    for (int c = 0; c < 6; c++)
#pragma unroll
      for (int r = 0; r < 4; r++) {
        int row = rowbase + s * 16 + quad * 4 + r;  // C/D: col=lane&15, row=quad*4+reg
        if (row < n_nodes)
          Z[(size_t)row * DZ + (w * 6 + c) * 16 + m16] = f2bf(acc[s][c][r]);
      }
}

// ---------------------------------------------------------------------------
// CSR build: count -> scan (3 kernels) -> fill
// ---------------------------------------------------------------------------
__global__ void count_kernel(const int* __restrict__ dst, int* __restrict__ cnt,
                             int E) {
  int e = blockIdx.x * 256 + threadIdx.x;
  if (e < E) atomicAdd(&cnt[dst[e]], 1);
}

__global__ __launch_bounds__(256) void scan1_kernel(
    const int* __restrict__ cnt, int* __restrict__ rowptr,
    int* __restrict__ bsum, int n) {
  __shared__ int sd[256];
  int t = threadIdx.x;
  int base = blockIdx.x * 1024 + t * 4;
  int v0 = base + 0 < n ? cnt[base + 0] : 0;
  int v1 = base + 1 < n ? cnt[base + 1] : 0;
  int v2 = base + 2 < n ? cnt[base + 2] : 0;
  int v3 = base + 3 < n ? cnt[base + 3] : 0;
  int tsum = v0 + v1 + v2 + v3;
  sd[t] = tsum;
  __syncthreads();
  for (int off = 1; off < 256; off <<= 1) {
    int add = (t >= off) ? sd[t - off] : 0;
    __syncthreads();
    sd[t] += add;
    __syncthreads();
  }
  int excl = sd[t] - tsum;
  if (base + 0 < n) rowptr[base + 0] = excl;
  if (base + 1 < n) rowptr[base + 1] = excl + v0;
  if (base + 2 < n) rowptr[base + 2] = excl + v0 + v1;
  if (base + 3 < n) rowptr[base + 3] = excl + v0 + v1 + v2;
  if (t == 255) bsum[blockIdx.x] = sd[255];
}

__global__ __launch_bounds__(128) void scan2_kernel(int* __restrict__ bsum,
                                                    int nb) {
  __shared__ int sd[128];
  int t = threadIdx.x;
  int v = t < nb ? bsum[t] : 0;
  sd[t] = v;
  __syncthreads();
  for (int off = 1; off < 128; off <<= 1) {
    int add = (t >= off) ? sd[t - off] : 0;
    __syncthreads();
    sd[t] += add;
    __syncthreads();
  }
  if (t < nb) bsum[t] = sd[t] - v;  // exclusive
}

__global__ void scan3_kernel(int* __restrict__ rowptr, int* __restrict__ cursor,
                             const int* __restrict__ bsum, int n) {
  int i = blockIdx.x * 256 + threadIdx.x;
  if (i < n) {
    int r = rowptr[i] + bsum[i >> 10];
    rowptr[i] = r;
    cursor[i] = r;
  }
}

__global__ void fill_kernel(const int* __restrict__ src,
                            const int* __restrict__ dst,
                            const float* __restrict__ wlo,
                            const float* __restrict__ whi,
                            int* __restrict__ cursor, int* __restrict__ srcS,
                            float2* __restrict__ wPair, int E) {
  int e = blockIdx.x * 256 + threadIdx.x;
  if (e < E) {
    int d = dst[e];
    int pos = atomicAdd(&cursor[d], 1);
    srcS[pos] = src[e];
    wPair[pos] = make_float2(wlo[e], whi[e]);
  }
}

// ---------------------------------------------------------------------------
// K_node: CSR gather + relu + attention3. One wave per node.
// Lane l<32: low-branch dims 4l..4l+3; lane l>=32: high-branch dims 4(l-32)..
// -> one uint2 (8B) load per edge covers both branches (512 B/wave).
// ---------------------------------------------------------------------------
__global__ __launch_bounds__(64) void node_kernel(
    const unsigned short* __restrict__ Zh, const int* __restrict__ rowptr,
    const int* __restrict__ cnt, const int* __restrict__ srcS,
    const float2* __restrict__ wPair, const float* __restrict__ a_low,
    const float* __restrict__ a_high, const float* __restrict__ a_mlp,
    const float* __restrict__ att_vec, float* __restrict__ out) {
  const int node = blockIdx.x;
  const int lane = threadIdx.x;
  const int isHigh = lane >> 5;     // 0: low branch, 1: high branch
  const int dbase = (lane & 31) * 4;
  const char* Zb = (const char*)Zh;

  const int start = rowptr[node];
  const int end = start + cnt[node];

  float acc0 = 0.f, acc1 = 0.f, acc2 = 0.f, acc3 = 0.f;
  int j = start;
  for (; j + 1 < end; j += 2) {
    int sA = srcS[j], sB = srcS[j + 1];
    float2 wA = wPair[j], wB = wPair[j + 1];
    float wa = isHigh ? wA.y : wA.x;
    float wb = isHigh ? wB.y : wB.x;
    uint2 zA = *(const uint2*)(Zb + (size_t)sA * 768 + lane * 8);
    uint2 zB = *(const uint2*)(Zb + (size_t)sB * 768 + lane * 8);
    acc0 += wa * __uint_as_float(zA.x << 16);
    acc1 += wa * __uint_as_float(zA.x & 0xffff0000u);
    acc2 += wa * __uint_as_float(zA.y << 16);
    acc3 += wa * __uint_as_float(zA.y & 0xffff0000u);
    acc0 += wb * __uint_as_float(zB.x << 16);
    acc1 += wb * __uint_as_float(zB.x & 0xffff0000u);
    acc2 += wb * __uint_as_float(zB.y << 16);
    acc3 += wb * __uint_as_float(zB.y & 0xffff0000u);
  }
  if (j < end) {
    int sA = srcS[j];
    float2 wA = wPair[j];
    float wa = isHigh ? wA.y : wA.x;
    uint2 zA = *(const uint2*)(Zb + (size_t)sA * 768 + lane * 8);
    acc0 += wa * __uint_as_float(zA.x << 16);
    acc1 += wa * __uint_as_float(zA.x & 0xffff0000u);
    acc2 += wa * __uint_as_float(zA.y << 16);
    acc3 += wa * __uint_as_float(zA.y & 0xffff0000u);
  }

  // relu -> h holds h_low dims (low lanes) or h_high dims (high lanes)
  float h0 = fmaxf(acc0, 0.f), h1 = fmaxf(acc1, 0.f);
  float h2 = fmaxf(acc2, 0.f), h3 = fmaxf(acc3, 0.f);

  // mlp branch (low lanes use it; high lanes compute duplicate, unused)
  uint2 zm = *(const uint2*)(Zb + (size_t)node * 768 + 512 + (size_t)(lane & 31) * 8);
  float q0 = fmaxf(__uint_as_float(zm.x << 16), 0.f);
  float q1 = fmaxf(__uint_as_float(zm.x & 0xffff0000u), 0.f);
  float q2 = fmaxf(__uint_as_float(zm.y << 16), 0.f);
  float q3 = fmaxf(__uint_as_float(zm.y & 0xffff0000u), 0.f);

  // per-branch attention dot partials
  const float* av_b = isHigh ? a_high : a_low;
  float4 ab = *(const float4*)&av_b[dbase];
  float4 am = *(const float4*)&a_mlp[dbase];
  float v1 = h0 * ab.x + h1 * ab.y + h2 * ab.z + h3 * ab.w;  // plo or phi
  float v2 = isHigh ? 0.f : (q0 * am.x + q1 * am.y + q2 * am.z + q3 * am.w);
#pragma unroll
  for (int off = 1; off < 32; off <<= 1) {
    v1 += __shfl_xor(v1, off);
    v2 += __shfl_xor(v2, off);
  }
  float s_lo = __shfl(v1, 0);
  float s_hi = __shfl(v1, 32);
  float s_ml = __shfl(v2, 0);

  // sigmoid -> 3x3 mix /3 -> softmax(T=3)
  float g0 = 1.f / (1.f + __expf(-s_lo));
  float g1 = 1.f / (1.f + __expf(-s_hi));
  float g2 = 1.f / (1.f + __expf(-s_ml));
  const float inv3 = 1.f / 3.f;
  float m0 = (g0 * att_vec[0] + g1 * att_vec[3] + g2 * att_vec[6]) * inv3;
  float m1 = (g0 * att_vec[1] + g1 * att_vec[4] + g2 * att_vec[7]) * inv3;
  float m2 = (g0 * att_vec[2] + g1 * att_vec[5] + g2 * att_vec[8]) * inv3;
  float mx = fmaxf(m0, fmaxf(m1, m2));
  float e0 = __expf(m0 - mx), e1 = __expf(m1 - mx), e2 = __expf(m2 - mx);
  float inv = 1.f / (e0 + e1 + e2);
  float c0 = 3.f * inv * e0, c1 = 3.f * inv * e1, c2 = 3.f * inv * e2;

  // bring h_high dims to low lanes
  float hh0 = __shfl_xor(h0, 32);
  float hh1 = __shfl_xor(h1, 32);
  float hh2 = __shfl_xor(h2, 32);
  float hh3 = __shfl_xor(h3, 32);

  if (!isHigh) {
    float4 o;
    o.x = c0 * h0 + c1 * hh0 + c2 * q0;
    o.y = c0 * h1 + c1 * hh1 + c2 * q1;
    o.z = c0 * h2 + c1 * hh2 + c2 * q2;
    o.w = c0 * h3 + c1 * hh3 + c2 * q3;
    *(float4*)&out[(size_t)node * D_OUT + dbase] = o;
  }
}

// ---------------------------------------------------------------------------
extern "C" void kernel_launch(void* const* d_in, const int* in_sizes, int n_in,
                              void* d_out, int out_size, void* d_ws,
                              size_t ws_size, hipStream_t stream) {
  const float* x    = (const float*)d_in[0];
  const int*   esrc = (const int*)d_in[1];
  const int*   edst = (const int*)d_in[2];
  const float* wlo  = (const float*)d_in[3];
  const float* whi  = (const float*)d_in[4];
  const float* Wl   = (const float*)d_in[6];
  const float* Wh   = (const float*)d_in[7];
  const float* Wm   = (const float*)d_in[8];
  const float* alo  = (const float*)d_in[9];
  const float* ahi  = (const float*)d_in[10];
  const float* amlp = (const float*)d_in[11];
  const float* av   = (const float*)d_in[12];
  float* out = (float*)d_out;

  const int N = in_sizes[0] / D_IN;  // 100000
  const int E = in_sizes[1];         // 1600000

  char* ws = (char*)d_ws;
  size_t off = 0;
  auto carve = [&](size_t bytes) -> void* {
    void* p = ws + off;
    off = (off + bytes + 255) & ~(size_t)255;
    return p;
  };
  unsigned short* Z     = (unsigned short*)carve((size_t)N * DZ * 2);
  unsigned short* Bpack = (unsigned short*)carve(98304 * 2);
  int*    cnt    = (int*)carve((size_t)N * 4);
  int*    rowptr = (int*)carve((size_t)N * 4);
  int*    cursor = (int*)carve((size_t)N * 4);
  int*    bsum   = (int*)carve(128 * 4);
  int*    srcS   = (int*)carve((size_t)E * 4);
  float2* wPair  = (float2*)carve((size_t)E * 8);

  repack_w_kernel<<<384, 256, 0, stream>>>(Wl, Wh, Wm, Bpack);

  gemm_kernel<<<(N + 63) / 64, 256, 0, stream>>>(x, Bpack, Z, N);

  hipMemsetAsync(cnt, 0, (size_t)N * 4, stream);
  count_kernel<<<(E + 255) / 256, 256, 0, stream>>>(edst, cnt, E);
  int nb = (N + 1023) / 1024;
  scan1_kernel<<<nb, 256, 0, stream>>>(cnt, rowptr, bsum, N);
  scan2_kernel<<<1, 128, 0, stream>>>(bsum, nb);
  scan3_kernel<<<(N + 255) / 256, 256, 0, stream>>>(rowptr, cursor, bsum, N);
  fill_kernel<<<(E + 255) / 256, 256, 0, stream>>>(esrc, edst, wlo, whi, cursor,
                                                   srcS, wPair, E);

  node_kernel<<<N, 64, 0, stream>>>(Z, rowptr, cnt, srcS, wPair, alo, ahi,
                                    amlp, av, out);
}

// Round 4
// 563.540 us; speedup vs baseline: 1.5918x; 1.0010x over previous
//
#include <hip/hip_runtime.h>
#include <hip/hip_bf16.h>
#include <math.h>

#define D_IN   256
#define D_OUT  128
#define DZ     384   // [low | high | mlp] bf16, 768 B per row

typedef __attribute__((ext_vector_type(8))) short short8;
typedef __attribute__((ext_vector_type(4))) float floatx4;

__device__ __forceinline__ unsigned short f2bf(float f) {
  union { float f; unsigned u; } v; v.f = f;
  unsigned r = v.u + 0x7fffu + ((v.u >> 16) & 1u);  // RNE
  return (unsigned short)(r >> 16);
}

// ---------------------------------------------------------------------------
// K0: pack [Wl|Wh|Wm] into MFMA B-fragment order.
// frag f = kt*24+nt holds B[k=kt*32+quad*8+j][n=nt*16+(lane&15)]
// flat index t = f*512 + lane*8 + j.
// ---------------------------------------------------------------------------
__global__ void repack_w_kernel(const float* __restrict__ Wl,
                                const float* __restrict__ Wh,
                                const float* __restrict__ Wm,
                                unsigned short* __restrict__ Bpack) {
  int t = blockIdx.x * 256 + threadIdx.x;  // 0..98303
  int j = t & 7;
  int lane = (t >> 3) & 63;
  int f = t >> 9;          // 0..191
  int nt = f % 24, kt = f / 24;
  int k = kt * 32 + (lane >> 4) * 8 + j;
  int n = nt * 16 + (lane & 15);
  const float* W = (n < 128) ? Wl : (n < 256 ? Wh : Wm);
  Bpack[t] = f2bf(W[k * D_OUT + (n & 127)]);
}

// ---------------------------------------------------------------------------
// K0b: x (fp32) -> xb (bf16), 8 elems/thread, 16B stores.
// ---------------------------------------------------------------------------
__global__ void xcvt_kernel(const float* __restrict__ x,
                            unsigned short* __restrict__ xb, int n8) {
  int i = blockIdx.x * 256 + threadIdx.x;
  if (i < n8) {
    const float4* p = (const float4*)x + (size_t)i * 2;
    float4 f0 = p[0], f1 = p[1];
    short8 o;
    o[0] = (short)f2bf(f0.x); o[1] = (short)f2bf(f0.y);
    o[2] = (short)f2bf(f0.z); o[3] = (short)f2bf(f0.w);
    o[4] = (short)f2bf(f1.x); o[5] = (short)f2bf(f1.y);
    o[6] = (short)f2bf(f1.z); o[7] = (short)f2bf(f1.w);
    ((short8*)xb)[i] = o;
  }
}

// ---------------------------------------------------------------------------
// K1: Z = xb @ [Wl|Wh|Wm], bf16 MFMA, 64x96 wave tile (4 strips x 6 ctiles).
// bf16 A: one 16B load per strip per kt, no cvt in loop. LDS-staged epilogue
// for coalesced 16B Z stores.
// ---------------------------------------------------------------------------
#define LDSROW 400  // shorts per padded row: 800 B, 16B aligned, quad-spread
__global__ __launch_bounds__(256, 3) void gemm_kernel(
    const unsigned short* __restrict__ xb,
    const unsigned short* __restrict__ Bpack, unsigned short* __restrict__ Z,
    int n_nodes) {
  __shared__ unsigned short tile[64 * LDSROW];
  const int lane = threadIdx.x & 63;
  const int w = threadIdx.x >> 6;  // wave id: column group
  const int rowbase = blockIdx.x * 64;
  const int m16 = lane & 15, quad = lane >> 4;

  floatx4 acc[4][6];
#pragma unroll
  for (int s = 0; s < 4; s++)
#pragma unroll
    for (int c = 0; c < 6; c++) acc[s][c] = (floatx4)(0.f);

  const short8* xr[4];
#pragma unroll
  for (int s = 0; s < 4; s++) {
    int r = rowbase + s * 16 + m16;
    if (r > n_nodes - 1) r = n_nodes - 1;  // clamp; stores are guarded
    xr[s] = (const short8*)xb + (size_t)r * 32 + quad;  // row*256/8 + quad
  }
  const short8* bp = (const short8*)Bpack + lane;

#pragma unroll
  for (int kt = 0; kt < 8; kt++) {
    short8 a[4];
#pragma unroll
    for (int s = 0; s < 4; s++) a[s] = xr[s][kt * 4];
#pragma unroll
    for (int c = 0; c < 6; c++) {
      short8 b = bp[(kt * 24 + w * 6 + c) * 64];
#pragma unroll
      for (int s = 0; s < 4; s++)
        acc[s][c] =
            __builtin_amdgcn_mfma_f32_16x16x32_bf16(a[s], b, acc[s][c], 0, 0, 0);
    }
  }

  // stage to LDS in C-layout (row = s*16+quad*4+r, col = (w*6+c)*16+m16)
#pragma unroll
  for (int s = 0; s < 4; s++)
#pragma unroll
    for (int c = 0; c < 6; c++)
#pragma unroll
      for (int r = 0; r < 4; r++)
        tile[(s * 16 + quad * 4 + r) * LDSROW + (w * 6 + c) * 16 + m16] =
            f2bf(acc[s][c][r]);
  __syncthreads();

  // coalesced store: 64 rows x 48 chunks of 16B
#pragma unroll
  for (int it = 0; it < 12; it++) {
    int chunk = it * 256 + threadIdx.x;
    int row = chunk / 48, col = (chunk % 48) * 8;
    int grow = rowbase + row;
    if (grow < n_nodes)
      *(short8*)(Z + (size_t)grow * DZ + col) =
          *(const short8*)&tile[row * LDSROW + col];
  }
}

// ---------------------------------------------------------------------------
// CSR build: count -> scan -> fill (meta = {src, packed bf16 (wl,wh)})
// ---------------------------------------------------------------------------
__global__ void count_kernel(const int* __restrict__ dst, int* __restrict__ cnt,
                             int E) {
  int e = blockIdx.x * 256 + threadIdx.x;
  if (e < E) atomicAdd(&cnt[dst[e]], 1);
}

__global__ __launch_bounds__(256) void scan1_kernel(
    const int* __restrict__ cnt, int* __restrict__ rowptr,
    int* __restrict__ bsum, int n) {
  __shared__ int sd[256];
  int t = threadIdx.x;
  int base = blockIdx.x * 1024 + t * 4;
  int v0 = base + 0 < n ? cnt[base + 0] : 0;
  int v1 = base + 1 < n ? cnt[base + 1] : 0;
  int v2 = base + 2 < n ? cnt[base + 2] : 0;
  int v3 = base + 3 < n ? cnt[base + 3] : 0;
  int tsum = v0 + v1 + v2 + v3;
  sd[t] = tsum;
  __syncthreads();
  for (int off = 1; off < 256; off <<= 1) {
    int add = (t >= off) ? sd[t - off] : 0;
    __syncthreads();
    sd[t] += add;
    __syncthreads();
  }
  int excl = sd[t] - tsum;
  if (base + 0 < n) rowptr[base + 0] = excl;
  if (base + 1 < n) rowptr[base + 1] = excl + v0;
  if (base + 2 < n) rowptr[base + 2] = excl + v0 + v1;
  if (base + 3 < n) rowptr[base + 3] = excl + v0 + v1 + v2;
  if (t == 255) bsum[blockIdx.x] = sd[255];
}

__global__ __launch_bounds__(128) void scan2_kernel(int* __restrict__ bsum,
                                                    int nb) {
  __shared__ int sd[128];
  int t = threadIdx.x;
  int v = t < nb ? bsum[t] : 0;
  sd[t] = v;
  __syncthreads();
  for (int off = 1; off < 128; off <<= 1) {
    int add = (t >= off) ? sd[t - off] : 0;
    __syncthreads();
    sd[t] += add;
    __syncthreads();
  }
  if (t < nb) bsum[t] = sd[t] - v;  // exclusive
}

__global__ void scan3_kernel(int* __restrict__ rowptr, int* __restrict__ cursor,
                             const int* __restrict__ bsum, int n, int E) {
  int i = blockIdx.x * 256 + threadIdx.x;
  if (i < n) {
    int r = rowptr[i] + bsum[i >> 10];
    rowptr[i] = r;
    cursor[i] = r;
    if (i == 0) rowptr[n] = E;
  }
}

__global__ void fill_kernel(const int* __restrict__ src,
                            const int* __restrict__ dst,
                            const float* __restrict__ wlo,
                            const float* __restrict__ whi,
                            int* __restrict__ cursor, uint2* __restrict__ meta,
                            int E) {
  int e = blockIdx.x * 256 + threadIdx.x;
  if (e < E) {
    int d = dst[e];
    int pos = atomicAdd(&cursor[d], 1);
    unsigned wl = f2bf(wlo[e]), wh = f2bf(whi[e]);
    meta[pos] = make_uint2((unsigned)src[e], wl | (wh << 16));
  }
}

// ---------------------------------------------------------------------------
// K_node: CSR gather + relu + attention3. 128-thr blocks = 2 independent
// waves = 2 nodes (no syncs). Lane l<32: low dims 4l..4l+3; l>=32: high dims.
// One uint2 Z load + one uint2 scalar meta load per edge, unroll x4.
// ---------------------------------------------------------------------------
__global__ __launch_bounds__(128) void node_kernel(
    const unsigned short* __restrict__ Zh, const int* __restrict__ rowptr,
    const uint2* __restrict__ meta, const float* __restrict__ a_low,
    const float* __restrict__ a_high, const float* __restrict__ a_mlp,
    const float* __restrict__ att_vec, float* __restrict__ out, int n_nodes) {
  const int node = blockIdx.x * 2 + (threadIdx.x >> 6);
  if (node >= n_nodes) return;
  const int lane = threadIdx.x & 63;
  const int isHigh = lane >> 5;
  const int dbase = (lane & 31) * 4;
  const char* Zb = (const char*)Zh;

  const int start = rowptr[node];
  const int end = rowptr[node + 1];

  float acc0 = 0.f, acc1 = 0.f, acc2 = 0.f, acc3 = 0.f;
  const unsigned wsh = isHigh ? 0 : 16;  // shift to select packed bf16 weight
  auto wsel = [&](unsigned p) {
    return __uint_as_float(isHigh ? (p & 0xffff0000u) : (p << 16));
  };
  auto step = [&](uint2 z, float wv) {
    acc0 += wv * __uint_as_float(z.x << 16);
    acc1 += wv * __uint_as_float(z.x & 0xffff0000u);
    acc2 += wv * __uint_as_float(z.y << 16);
    acc3 += wv * __uint_as_float(z.y & 0xffff0000u);
  };

  int j = start;
  const int nfull = (end - start) & ~3;
  for (; j < start + nfull; j += 4) {
    uint2 m0 = meta[j], m1 = meta[j + 1], m2 = meta[j + 2], m3 = meta[j + 3];
    uint2 z0 = *(const uint2*)(Zb + (size_t)m0.x * 768 + lane * 8);
    uint2 z1 = *(const uint2*)(Zb + (size_t)m1.x * 768 + lane * 8);
    uint2 z2 = *(const uint2*)(Zb + (size_t)m2.x * 768 + lane * 8);
    uint2 z3 = *(const uint2*)(Zb + (size_t)m3.x * 768 + lane * 8);
    step(z0, wsel(m0.y));
    step(z1, wsel(m1.y));
    step(z2, wsel(m2.y));
    step(z3, wsel(m3.y));
  }
  for (; j < end; j++) {
    uint2 m0 = meta[j];
    uint2 z0 = *(const uint2*)(Zb + (size_t)m0.x * 768 + lane * 8);
    step(z0, wsel(m0.y));
  }
  (void)wsh;

  float h0 = fmaxf(acc0, 0.f), h1 = fmaxf(acc1, 0.f);
  float h2 = fmaxf(acc2, 0.f), h3 = fmaxf(acc3, 0.f);

  uint2 zm =
      *(const uint2*)(Zb + (size_t)node * 768 + 512 + (size_t)(lane & 31) * 8);
  float q0 = fmaxf(__uint_as_float(zm.x << 16), 0.f);
  float q1 = fmaxf(__uint_as_float(zm.x & 0xffff0000u), 0.f);
  float q2 = fmaxf(__uint_as_float(zm.y << 16), 0.f);
  float q3 = fmaxf(__uint_as_float(zm.y & 0xffff0000u), 0.f);

  const float* av_b = isHigh ? a_high : a_low;
  float4 ab = *(const float4*)&av_b[dbase];
  float4 am = *(const float4*)&a_mlp[dbase];
  float v1 = h0 * ab.x + h1 * ab.y + h2 * ab.z + h3 * ab.w;
  float v2 = isHigh ? 0.f : (q0 * am.x + q1 * am.y + q2 * am.z + q3 * am.w);
#pragma unroll
  for (int off = 1; off < 32; off <<= 1) {
    v1 += __shfl_xor(v1, off);
    v2 += __shfl_xor(v2, off);
  }
  float s_lo = __shfl(v1, 0);
  float s_hi = __shfl(v1, 32);
  float s_ml = __shfl(v2, 0);

  float g0 = 1.f / (1.f + __expf(-s_lo));
  float g1 = 1.f / (1.f + __expf(-s_hi));
  float g2 = 1.f / (1.f + __expf(-s_ml));
  const float inv3 = 1.f / 3.f;
  float m0 = (g0 * att_vec[0] + g1 * att_vec[3] + g2 * att_vec[6]) * inv3;
  float m1 = (g0 * att_vec[1] + g1 * att_vec[4] + g2 * att_vec[7]) * inv3;
  float m2 = (g0 * att_vec[2] + g1 * att_vec[5] + g2 * att_vec[8]) * inv3;
  float mx = fmaxf(m0, fmaxf(m1, m2));
  float e0 = __expf(m0 - mx), e1 = __expf(m1 - mx), e2 = __expf(m2 - mx);
  float inv = 1.f / (e0 + e1 + e2);
  float c0 = 3.f * inv * e0, c1 = 3.f * inv * e1, c2 = 3.f * inv * e2;

  float hh0 = __shfl_xor(h0, 32);
  float hh1 = __shfl_xor(h1, 32);
  float hh2 = __shfl_xor(h2, 32);
  float hh3 = __shfl_xor(h3, 32);

  if (!isHigh) {
    float4 o;
    o.x = c0 * h0 + c1 * hh0 + c2 * q0;
    o.y = c0 * h1 + c1 * hh1 + c2 * q1;
    o.z = c0 * h2 + c1 * hh2 + c2 * q2;
    o.w = c0 * h3 + c1 * hh3 + c2 * q3;
    *(float4*)&out[(size_t)node * D_OUT + dbase] = o;
  }
}

// ---------------------------------------------------------------------------
extern "C" void kernel_launch(void* const* d_in, const int* in_sizes, int n_in,
                              void* d_out, int out_size, void* d_ws,
                              size_t ws_size, hipStream_t stream) {
  const float* x    = (const float*)d_in[0];
  const int*   esrc = (const int*)d_in[1];
  const int*   edst = (const int*)d_in[2];
  const float* wlo  = (const float*)d_in[3];
  const float* whi  = (const float*)d_in[4];
  const float* Wl   = (const float*)d_in[6];
  const float* Wh   = (const float*)d_in[7];
  const float* Wm   = (const float*)d_in[8];
  const float* alo  = (const float*)d_in[9];
  const float* ahi  = (const float*)d_in[10];
  const float* amlp = (const float*)d_in[11];
  const float* av   = (const float*)d_in[12];
  float* out = (float*)d_out;

  const int N = in_sizes[0] / D_IN;  // 100000
  const int E = in_sizes[1];         // 1600000

  char* ws = (char*)d_ws;
  size_t off = 0;
  auto carve = [&](size_t bytes) -> void* {
    void* p = ws + off;
    off = (off + bytes + 255) & ~(size_t)255;
    return p;
  };
  unsigned short* Z     = (unsigned short*)carve((size_t)N * DZ * 2);
  unsigned short* xb    = (unsigned short*)carve((size_t)N * D_IN * 2);
  unsigned short* Bpack = (unsigned short*)carve(98304 * 2);
  int*   cnt    = (int*)carve((size_t)N * 4);
  int*   rowptr = (int*)carve((size_t)(N + 1) * 4);
  int*   cursor = (int*)carve((size_t)N * 4);
  int*   bsum   = (int*)carve(128 * 4);
  uint2* meta   = (uint2*)carve((size_t)E * 8);

  repack_w_kernel<<<384, 256, 0, stream>>>(Wl, Wh, Wm, Bpack);
  int n8 = in_sizes[0] / 8;
  xcvt_kernel<<<(n8 + 255) / 256, 256, 0, stream>>>(x, xb, n8);

  gemm_kernel<<<(N + 63) / 64, 256, 0, stream>>>(xb, Bpack, Z, N);

  hipMemsetAsync(cnt, 0, (size_t)N * 4, stream);
  count_kernel<<<(E + 255) / 256, 256, 0, stream>>>(edst, cnt, E);
  int nb = (N + 1023) / 1024;
  scan1_kernel<<<nb, 256, 0, stream>>>(cnt, rowptr, bsum, N);
  scan2_kernel<<<1, 128, 0, stream>>>(bsum, nb);
  scan3_kernel<<<(N + 255) / 256, 256, 0, stream>>>(rowptr, cursor, bsum, N, E);
  fill_kernel<<<(E + 255) / 256, 256, 0, stream>>>(esrc, edst, wlo, whi, cursor,
                                                   meta, E);

  node_kernel<<<(N + 1) / 2, 128, 0, stream>>>(Z, rowptr, meta, alo, ahi, amlp,
                                               av, out, N);
}

// Round 5
// 505.980 us; speedup vs baseline: 1.7729x; 1.1138x over previous
//
#include <hip/hip_runtime.h>
#include <hip/hip_bf16.h>
#include <math.h>

#define D_IN   256
#define D_OUT  128
#define DZ     384   // [low | high | mlp] bf16, 768 B per row

typedef __attribute__((ext_vector_type(8))) short short8;
typedef __attribute__((ext_vector_type(4))) float floatx4;

__device__ __forceinline__ unsigned short f2bf(float f) {
  union { float f; unsigned u; } v; v.f = f;
  unsigned r = v.u + 0x7fffu + ((v.u >> 16) & 1u);  // RNE
  return (unsigned short)(r >> 16);
}

// ---------------------------------------------------------------------------
// K0: pack [Wl|Wh|Wm] into MFMA B-fragment order.
// frag f = kt*24+nt holds B[k=kt*32+quad*8+j][n=nt*16+(lane&15)]
// flat index t = f*512 + lane*8 + j.
// ---------------------------------------------------------------------------
__global__ void repack_w_kernel(const float* __restrict__ Wl,
                                const float* __restrict__ Wh,
                                const float* __restrict__ Wm,
                                unsigned short* __restrict__ Bpack) {
  int t = blockIdx.x * 256 + threadIdx.x;  // 0..98303
  int j = t & 7;
  int lane = (t >> 3) & 63;
  int f = t >> 9;          // 0..191
  int nt = f % 24, kt = f / 24;
  int k = kt * 32 + (lane >> 4) * 8 + j;
  int n = nt * 16 + (lane & 15);
  const float* W = (n < 128) ? Wl : (n < 256 ? Wh : Wm);
  Bpack[t] = f2bf(W[k * D_OUT + (n & 127)]);
}

// ---------------------------------------------------------------------------
// K0b: x (fp32) -> xb (bf16), 8 elems/thread, 16B stores.
// ---------------------------------------------------------------------------
__global__ void xcvt_kernel(const float* __restrict__ x,
                            unsigned short* __restrict__ xb, int n8) {
  int i = blockIdx.x * 256 + threadIdx.x;
  if (i < n8) {
    const float4* p = (const float4*)x + (size_t)i * 2;
    float4 f0 = p[0], f1 = p[1];
    short8 o;
    o[0] = (short)f2bf(f0.x); o[1] = (short)f2bf(f0.y);
    o[2] = (short)f2bf(f0.z); o[3] = (short)f2bf(f0.w);
    o[4] = (short)f2bf(f1.x); o[5] = (short)f2bf(f1.y);
    o[6] = (short)f2bf(f1.z); o[7] = (short)f2bf(f1.w);
    ((short8*)xb)[i] = o;
  }
}

// ---------------------------------------------------------------------------
// K1: Z = xb @ [Wl|Wh|Wm], bf16 MFMA. 512-thr block = 8 waves over the same
// 64 rows; wave w owns ctiles w*3..w*3+2 (acc 4 strips x 3 ctiles = 48 AGPR).
// launch_bounds(512,4) -> 2 blocks/CU -> 4 waves/SIMD for latency hiding.
// A-strip loads use compile-time offsets; A shared across 8 waves via L1;
// B (192 KB) is XCD-L2-resident. LDS-staged epilogue, 16B coalesced stores.
// ---------------------------------------------------------------------------
#define LDSROW 392  // shorts/row: 784 B (16B-aligned); 4-row stride = 16 mod 32
__global__ __launch_bounds__(512, 4) void gemm_kernel(
    const unsigned short* __restrict__ xb,
    const unsigned short* __restrict__ Bpack, unsigned short* __restrict__ Z,
    int n_nodes) {
  __shared__ unsigned short tile[64 * LDSROW];
  const int lane = threadIdx.x & 63;
  const int w = threadIdx.x >> 6;  // 0..7: column group (3 ctiles)
  const int rowbase = blockIdx.x * 64;
  const int m16 = lane & 15, quad = lane >> 4;

  floatx4 acc[4][3];
#pragma unroll
  for (int s = 0; s < 4; s++)
#pragma unroll
    for (int c = 0; c < 3; c++) acc[s][c] = (floatx4)(0.f);

  const short8* xr[4];
#pragma unroll
  for (int s = 0; s < 4; s++) {
    int r = rowbase + s * 16 + m16;
    if (r > n_nodes - 1) r = n_nodes - 1;  // clamp; stores are guarded
    xr[s] = (const short8*)xb + (size_t)r * 32 + quad;  // row*256/8 + quad
  }
  const short8* bp = (const short8*)Bpack + lane;

#pragma unroll
  for (int kt = 0; kt < 8; kt++) {
    short8 a[4];
#pragma unroll
    for (int s = 0; s < 4; s++) a[s] = xr[s][kt * 4];
#pragma unroll
    for (int c = 0; c < 3; c++) {
      short8 b = bp[(kt * 24 + w * 3 + c) * 64];
#pragma unroll
      for (int s = 0; s < 4; s++)
        acc[s][c] =
            __builtin_amdgcn_mfma_f32_16x16x32_bf16(a[s], b, acc[s][c], 0, 0, 0);
    }
  }

  // stage to LDS in C-layout (row = s*16+quad*4+r, col = (w*3+c)*16+m16)
#pragma unroll
  for (int s = 0; s < 4; s++)
#pragma unroll
    for (int c = 0; c < 3; c++)
#pragma unroll
      for (int r = 0; r < 4; r++)
        tile[(s * 16 + quad * 4 + r) * LDSROW + (w * 3 + c) * 16 + m16] =
            f2bf(acc[s][c][r]);
  __syncthreads();

  // coalesced store: 64 rows x 48 chunks of 16B = 3072 chunks / 512 thr
#pragma unroll
  for (int it = 0; it < 6; it++) {
    int chunk = it * 512 + threadIdx.x;
    int row = chunk / 48, col = (chunk % 48) * 8;
    int grow = rowbase + row;
    if (grow < n_nodes)
      *(short8*)(Z + (size_t)grow * DZ + col) =
          *(const short8*)&tile[row * LDSROW + col];
  }
}

// ---------------------------------------------------------------------------
// CSR build, rank-based (single atomic pass):
//   rank_kernel: rank[e] = atomicAdd(cnt[dst],1)   (only atomics in pipeline)
//   scan1/2/3 : exclusive scan of cnt -> rowptr (+ rowptr[N]=E)
//   scatter   : meta[rowptr[dst]+rank[e]] = {src, bf16(wl)|bf16(wh)<<16}
// ---------------------------------------------------------------------------
__global__ void rank_kernel(const int* __restrict__ dst, int* __restrict__ cnt,
                            int* __restrict__ rank, int E) {
  int e = (blockIdx.x * 256 + threadIdx.x) * 4;
  if (e + 3 < E) {
    int4 d = *(const int4*)&dst[e];
    int r0 = atomicAdd(&cnt[d.x], 1);
    int r1 = atomicAdd(&cnt[d.y], 1);
    int r2 = atomicAdd(&cnt[d.z], 1);
    int r3 = atomicAdd(&cnt[d.w], 1);
    *(int4*)&rank[e] = make_int4(r0, r1, r2, r3);
  } else {
    for (int k = e; k < E; k++) rank[k] = atomicAdd(&cnt[dst[k]], 1);
  }
}

__global__ __launch_bounds__(256) void scan1_kernel(
    const int* __restrict__ cnt, int* __restrict__ rowptr,
    int* __restrict__ bsum, int n) {
  __shared__ int sd[256];
  int t = threadIdx.x;
  int base = blockIdx.x * 1024 + t * 4;
  int v0 = base + 0 < n ? cnt[base + 0] : 0;
  int v1 = base + 1 < n ? cnt[base + 1] : 0;
  int v2 = base + 2 < n ? cnt[base + 2] : 0;
  int v3 = base + 3 < n ? cnt[base + 3] : 0;
  int tsum = v0 + v1 + v2 + v3;
  sd[t] = tsum;
  __syncthreads();
  for (int off = 1; off < 256; off <<= 1) {
    int add = (t >= off) ? sd[t - off] : 0;
    __syncthreads();
    sd[t] += add;
    __syncthreads();
  }
  int excl = sd[t] - tsum;
  if (base + 0 < n) rowptr[base + 0] = excl;
  if (base + 1 < n) rowptr[base + 1] = excl + v0;
  if (base + 2 < n) rowptr[base + 2] = excl + v0 + v1;
  if (base + 3 < n) rowptr[base + 3] = excl + v0 + v1 + v2;
  if (t == 255) bsum[blockIdx.x] = sd[255];
}

__global__ __launch_bounds__(128) void scan2_kernel(int* __restrict__ bsum,
                                                    int nb) {
  __shared__ int sd[128];
  int t = threadIdx.x;
  int v = t < nb ? bsum[t] : 0;
  sd[t] = v;
  __syncthreads();
  for (int off = 1; off < 128; off <<= 1) {
    int add = (t >= off) ? sd[t - off] : 0;
    __syncthreads();
    sd[t] += add;
    __syncthreads();
  }
  if (t < nb) bsum[t] = sd[t] - v;  // exclusive
}

__global__ void scan3_kernel(int* __restrict__ rowptr,
                             const int* __restrict__ bsum, int n, int E) {
  int i = blockIdx.x * 256 + threadIdx.x;
  if (i < n) {
    rowptr[i] = rowptr[i] + bsum[i >> 10];
    if (i == 0) rowptr[n] = E;
  }
}

__global__ void scatter_kernel(const int* __restrict__ src,
                               const int* __restrict__ dst,
                               const float* __restrict__ wlo,
                               const float* __restrict__ whi,
                               const int* __restrict__ rowptr,
                               const int* __restrict__ rank,
                               uint2* __restrict__ meta, int E) {
  int e = blockIdx.x * 256 + threadIdx.x;
  if (e < E) {
    int d = dst[e];
    int pos = rowptr[d] + rank[e];
    unsigned wl = f2bf(wlo[e]), wh = f2bf(whi[e]);
    meta[pos] = make_uint2((unsigned)src[e], wl | (wh << 16));
  }
}

// ---------------------------------------------------------------------------
// K_node: CSR gather + relu + attention3. 128-thr blocks = 2 independent
// waves = 2 nodes. readfirstlane(node) -> rowptr/meta via scalar loads.
// Lane l<32: low dims 4l..4l+3; l>=32: high dims. One uint2 Z load per edge,
// unroll x8 for MLP of gather latency.
// ---------------------------------------------------------------------------
__global__ __launch_bounds__(128) void node_kernel(
    const unsigned short* __restrict__ Zh, const int* __restrict__ rowptr,
    const uint2* __restrict__ meta, const float* __restrict__ a_low,
    const float* __restrict__ a_high, const float* __restrict__ a_mlp,
    const float* __restrict__ att_vec, float* __restrict__ out, int n_nodes) {
  int node = blockIdx.x * 2 + (threadIdx.x >> 6);
  if (node >= n_nodes) return;
  node = __builtin_amdgcn_readfirstlane(node);  // wave-uniform -> s_loads
  const int lane = threadIdx.x & 63;
  const int isHigh = lane >> 5;
  const int dbase = (lane & 31) * 4;
  const char* Zb = (const char*)Zh;

  const int start = rowptr[node];
  const int end = rowptr[node + 1];

  float acc0 = 0.f, acc1 = 0.f, acc2 = 0.f, acc3 = 0.f;
  auto wsel = [&](unsigned p) {
    return __uint_as_float(isHigh ? (p & 0xffff0000u) : (p << 16));
  };
  auto step = [&](uint2 z, float wv) {
    acc0 += wv * __uint_as_float(z.x << 16);
    acc1 += wv * __uint_as_float(z.x & 0xffff0000u);
    acc2 += wv * __uint_as_float(z.y << 16);
    acc3 += wv * __uint_as_float(z.y & 0xffff0000u);
  };

  int j = start;
  const int nfull = (end - start) & ~7;
  for (; j < start + nfull; j += 8) {
    uint2 m[8], z[8];
#pragma unroll
    for (int u = 0; u < 8; u++) m[u] = meta[j + u];
#pragma unroll
    for (int u = 0; u < 8; u++)
      z[u] = *(const uint2*)(Zb + (size_t)m[u].x * 768 + lane * 8);
#pragma unroll
    for (int u = 0; u < 8; u++) step(z[u], wsel(m[u].y));
  }
  for (; j < end; j++) {
    uint2 m0 = meta[j];
    uint2 z0 = *(const uint2*)(Zb + (size_t)m0.x * 768 + lane * 8);
    step(z0, wsel(m0.y));
  }

  float h0 = fmaxf(acc0, 0.f), h1 = fmaxf(acc1, 0.f);
  float h2 = fmaxf(acc2, 0.f), h3 = fmaxf(acc3, 0.f);

  uint2 zm =
      *(const uint2*)(Zb + (size_t)node * 768 + 512 + (size_t)(lane & 31) * 8);
  float q0 = fmaxf(__uint_as_float(zm.x << 16), 0.f);
  float q1 = fmaxf(__uint_as_float(zm.x & 0xffff0000u), 0.f);
  float q2 = fmaxf(__uint_as_float(zm.y << 16), 0.f);
  float q3 = fmaxf(__uint_as_float(zm.y & 0xffff0000u), 0.f);

  const float* av_b = isHigh ? a_high : a_low;
  float4 ab = *(const float4*)&av_b[dbase];
  float4 am = *(const float4*)&a_mlp[dbase];
  float v1 = h0 * ab.x + h1 * ab.y + h2 * ab.z + h3 * ab.w;
  float v2 = isHigh ? 0.f : (q0 * am.x + q1 * am.y + q2 * am.z + q3 * am.w);
#pragma unroll
  for (int off = 1; off < 32; off <<= 1) {
    v1 += __shfl_xor(v1, off);
    v2 += __shfl_xor(v2, off);
  }
  float s_lo = __shfl(v1, 0);
  float s_hi = __shfl(v1, 32);
  float s_ml = __shfl(v2, 0);

  float g0 = 1.f / (1.f + __expf(-s_lo));
  float g1 = 1.f / (1.f + __expf(-s_hi));
  float g2 = 1.f / (1.f + __expf(-s_ml));
  const float inv3 = 1.f / 3.f;
  float m0 = (g0 * att_vec[0] + g1 * att_vec[3] + g2 * att_vec[6]) * inv3;
  float m1 = (g0 * att_vec[1] + g1 * att_vec[4] + g2 * att_vec[7]) * inv3;
  float m2 = (g0 * att_vec[2] + g1 * att_vec[5] + g2 * att_vec[8]) * inv3;
  float mx = fmaxf(m0, fmaxf(m1, m2));
  float e0 = __expf(m0 - mx), e1 = __expf(m1 - mx), e2 = __expf(m2 - mx);
  float inv = 1.f / (e0 + e1 + e2);
  float c0 = 3.f * inv * e0, c1 = 3.f * inv * e1, c2 = 3.f * inv * e2;

  float hh0 = __shfl_xor(h0, 32);
  float hh1 = __shfl_xor(h1, 32);
  float hh2 = __shfl_xor(h2, 32);
  float hh3 = __shfl_xor(h3, 32);

  if (!isHigh) {
    float4 o;
    o.x = c0 * h0 + c1 * hh0 + c2 * q0;
    o.y = c0 * h1 + c1 * hh1 + c2 * q1;
    o.z = c0 * h2 + c1 * hh2 + c2 * q2;
    o.w = c0 * h3 + c1 * hh3 + c2 * q3;
    *(float4*)&out[(size_t)node * D_OUT + dbase] = o;
  }
}

// ---------------------------------------------------------------------------
extern "C" void kernel_launch(void* const* d_in, const int* in_sizes, int n_in,
                              void* d_out, int out_size, void* d_ws,
                              size_t ws_size, hipStream_t stream) {
  const float* x    = (const float*)d_in[0];
  const int*   esrc = (const int*)d_in[1];
  const int*   edst = (const int*)d_in[2];
  const float* wlo  = (const float*)d_in[3];
  const float* whi  = (const float*)d_in[4];
  const float* Wl   = (const float*)d_in[6];
  const float* Wh   = (const float*)d_in[7];
  const float* Wm   = (const float*)d_in[8];
  const float* alo  = (const float*)d_in[9];
  const float* ahi  = (const float*)d_in[10];
  const float* amlp = (const float*)d_in[11];
  const float* av   = (const float*)d_in[12];
  float* out = (float*)d_out;

  const int N = in_sizes[0] / D_IN;  // 100000
  const int E = in_sizes[1];         // 1600000

  char* ws = (char*)d_ws;
  size_t off = 0;
  auto carve = [&](size_t bytes) -> void* {
    void* p = ws + off;
    off = (off + bytes + 255) & ~(size_t)255;
    return p;
  };
  unsigned short* Z     = (unsigned short*)carve((size_t)N * DZ * 2);
  unsigned short* xb    = (unsigned short*)carve((size_t)N * D_IN * 2);
  unsigned short* Bpack = (unsigned short*)carve(98304 * 2);
  int*   cnt    = (int*)carve((size_t)N * 4);
  int*   rowptr = (int*)carve((size_t)(N + 1) * 4);
  int*   rank   = (int*)carve((size_t)E * 4);
  int*   bsum   = (int*)carve(128 * 4);
  uint2* meta   = (uint2*)carve((size_t)E * 8);

  repack_w_kernel<<<384, 256, 0, stream>>>(Wl, Wh, Wm, Bpack);
  int n8 = in_sizes[0] / 8;
  xcvt_kernel<<<(n8 + 255) / 256, 256, 0, stream>>>(x, xb, n8);

  // CSR build (independent of gemm)
  hipMemsetAsync(cnt, 0, (size_t)N * 4, stream);
  rank_kernel<<<(E / 4 + 255) / 256, 256, 0, stream>>>(edst, cnt, rank, E);
  int nb = (N + 1023) / 1024;
  scan1_kernel<<<nb, 256, 0, stream>>>(cnt, rowptr, bsum, N);
  scan2_kernel<<<1, 128, 0, stream>>>(bsum, nb);
  scan3_kernel<<<(N + 255) / 256, 256, 0, stream>>>(rowptr, bsum, N, E);
  scatter_kernel<<<(E + 255) / 256, 256, 0, stream>>>(esrc, edst, wlo, whi,
                                                      rowptr, rank, meta, E);

  gemm_kernel<<<(N + 63) / 64, 512, 0, stream>>>(xb, Bpack, Z, N);

  node_kernel<<<(N + 1) / 2, 128, 0, stream>>>(Z, rowptr, meta, alo, ahi, amlp,
                                               av, out, N);
}